// Round 7
// baseline (308.521 us; speedup 1.0000x reference)
//
#include <hip/hip_runtime.h>

#define BATCH 8
#define CH    64
#define HH    112
#define WW    112
#define HW    (HH * WW)          // 12544
#define NP    (BATCH * HW)       // 100352 pixels
#define TAPS  25
#define MIDC  256
#define PIX   64                 // pixels per block (= 1 wave-width group)
#define CPW   16                 // channels per wave (4 waves * 16 = 64)
#define NBLK  (NP / PIX)         // 1568 blocks
#define NXCD  8
#define CPX   (NBLK / NXCD)      // 196 blocks per XCD == blocks per image

// ---------------------------------------------------------------------------
// Kernel A: fold conv2 (1x1, 256->25) into conv1 weights.
// R7: output layout changed to [i][c][j][o] (i=tap/5, j=tap%5) so the main
// kernel's per-(i,c) inner block reads 125 CONTIGUOUS floats (clean scalar
// s_load_dwordx16 streaming instead of 5 scattered 100B chunks).
//   weff[((i*CH + c)*5 + j)*25 + o] = sum_mid w2[o][mid] * w1[mid][c][i*5+j]
// ---------------------------------------------------------------------------
#define WEFF_N   (CH * TAPS * TAPS)   // 40000
#define WEFF_TOT (WEFF_N + TAPS)      // 40025 (beff appended)
__global__ __launch_bounds__(256) void weff_kernel(
    const float* __restrict__ w1, const float* __restrict__ b1,
    const float* __restrict__ w2, const float* __restrict__ b2,
    float* __restrict__ weff, float* __restrict__ beff) {
  __shared__ float part[3][64];              // chunks 1..3 park partials
  const int lane  = threadIdx.x & 63;
  const int chunk = threadIdx.x >> 6;        // mid in [chunk*64, chunk*64+64)
  const int id    = blockIdx.x * 64 + lane;

  float acc = 0.f;
  if (id < WEFF_N) {
    const int tap = id % TAPS;
    const int t2  = id / TAPS;
    const int o   = t2 % TAPS;
    const int c   = t2 / TAPS;
    const float* w2o = w2 + o * MIDC + chunk * 64;
    const float* w1p = w1 + ((size_t)(chunk * 64) * CH + c) * TAPS + tap;
    float a0 = 0.f, a1 = 0.f;
    #pragma unroll 8
    for (int m = 0; m < 64; m += 2) {
      a0 = fmaf(w1p[(size_t)m       * CH * TAPS], w2o[m],     a0);
      a1 = fmaf(w1p[(size_t)(m + 1) * CH * TAPS], w2o[m + 1], a1);
    }
    acc = a0 + a1;
  } else if (id < WEFF_TOT) {
    const int o = id - WEFF_N;
    const float* w2o = w2 + o * MIDC + chunk * 64;
    const float* b1p = b1 + chunk * 64;
    #pragma unroll 8
    for (int m = 0; m < 64; ++m) acc = fmaf(w2o[m], b1p[m], acc);
  }

  if (chunk) part[chunk - 1][lane] = acc;
  __syncthreads();
  if (chunk == 0 && id < WEFF_TOT) {
    float r = acc + part[0][lane] + part[1][lane] + part[2][lane];
    if (id < WEFF_N) {
      const int tap = id % TAPS;
      const int t2  = id / TAPS;
      const int o   = t2 % TAPS;
      const int c   = t2 / TAPS;
      const int ii  = tap / 5, jj = tap % 5;
      weff[(((size_t)ii * CH + c) * 5 + jj) * TAPS + o] = r;
    } else {
      beff[id - WEFF_N] = r + b2[id - WEFF_N];
    }
  }
}

// ---------------------------------------------------------------------------
// Kernel B. R7 change (phase 1 ONLY; reduce/softmax/phase2 verbatim R6):
// Per dilated row i, TWO loads per channel cover the block's 72-px window:
//   A = x[hw + dy*112 - 4]  (relative offsets -4..59 across the wave)
//   B = x[hw + dy*112 + 4]  (relative offsets  4..67)
// Tap j's value at offset 2j-4: j=0 -> A, j=4 -> B, j=1..3 via __shfl from
// A (lanes <= 63-2j) or B (high lanes). Consumer-side masking against the
// true (yy,xx) makes clamped/wrapped producer values unreachable -> exact.
// Loads: 400 -> 160/thread; L1 line-fetch demand ~3.3x lower (the five
// j-taps re-fetched the same ~6 lines/channel as 20 requests before).
// ---------------------------------------------------------------------------
__global__ __launch_bounds__(256, 6) void picanet_main(
    const float* __restrict__ x, const float* __restrict__ weff,
    const float* __restrict__ beff, float* __restrict__ out) {
  __shared__ float red[2 * PIX * TAPS];       // 12.8 KB

  const int lane = threadIdx.x & 63;
  const int wave = threadIdx.x >> 6;
  const int c0 = __builtin_amdgcn_readfirstlane(wave * CPW);

  // XCD-aware bijective remap: image b pinned to XCD b (3.2 MB < 4 MB L2).
  const int lb = (blockIdx.x & (NXCD - 1)) * CPX + (blockIdx.x >> 3);
  const int p  = lb * PIX + lane;             // NP % 64 == 0, no tail
  const int b  = p / HW;
  const int hw = p % HW;
  const int h  = hw / WW;
  const int w  = hw % WW;

  const float* xb = x + (size_t)b * CH * HW + (size_t)c0 * HW;

  // Column validity per j (depends only on w) and shuffle source lanes.
  bool colok[5];
  #pragma unroll
  for (int j = 0; j < 5; ++j) {
    int xx = w + 2 * j - 4;
    colok[j] = (xx >= 0) & (xx < WW);
  }
  const int a1 = lane + 2, a2 = lane + 4, a3 = lane + 6;
  const int b1i = lane - 6, b2i = lane - 4, b3i = lane - 2;

  // ---- Phase 1: partial logits over this wave's 16 channels ----
  float s[TAPS];
  #pragma unroll
  for (int o = 0; o < TAPS; ++o) s[o] = 0.f;

  #pragma unroll 1
  for (int i = 0; i < 5; ++i) {
    const int dy  = 2 * i - 4;
    const int yy  = h + dy;
    const bool rowok = (yy >= 0) & (yy < HH);
    if (!__any((int)rowok)) continue;         // whole-wave-skip border rows

    int ia = hw + dy * WW - 4;
    int ib = hw + dy * WW + 4;
    ia = min(max(ia, 0), HW - 1);             // clamped values never consumed
    ib = min(max(ib, 0), HW - 1);

    bool ok0 = rowok & colok[0], ok1 = rowok & colok[1];
    bool ok2 = rowok & colok[2], ok3 = rowok & colok[3];
    bool ok4 = rowok & colok[4];

    const float* wci = weff + ((size_t)i * CH + c0) * (5 * TAPS);

    #pragma unroll
    for (int c = 0; c < CPW; ++c) {
      const float A = xb[(size_t)c * HW + ia];
      const float B = xb[(size_t)c * HW + ib];

      // gather the 5 tap values for this (i, c)
      float sA1 = __shfl(A, a1), sB1 = __shfl(B, b1i);
      float sA2 = __shfl(A, a2), sB2 = __shfl(B, b2i);
      float sA3 = __shfl(A, a3), sB3 = __shfl(B, b3i);
      float v0 = ok0 ? A : 0.f;
      float v1 = ok1 ? ((lane <= 61) ? sA1 : sB1) : 0.f;
      float v2 = ok2 ? ((lane <= 59) ? sA2 : sB2) : 0.f;
      float v3 = ok3 ? ((lane <= 57) ? sA3 : sB3) : 0.f;
      float v4 = ok4 ? B : 0.f;

      const float* wp = wci + c * (5 * TAPS);  // 125 contiguous floats
      #pragma unroll
      for (int o = 0; o < TAPS; ++o) s[o] = fmaf(v0, wp[o],       s[o]);
      #pragma unroll
      for (int o = 0; o < TAPS; ++o) s[o] = fmaf(v1, wp[25 + o],  s[o]);
      #pragma unroll
      for (int o = 0; o < TAPS; ++o) s[o] = fmaf(v2, wp[50 + o],  s[o]);
      #pragma unroll
      for (int o = 0; o < TAPS; ++o) s[o] = fmaf(v3, wp[75 + o],  s[o]);
      #pragma unroll
      for (int o = 0; o < TAPS; ++o) s[o] = fmaf(v4, wp[100 + o], s[o]);
    }
  }

  // ---- Tree reduce across waves (12.8 KB) ----
  if (wave >= 2) {
    float* dst = red + (wave - 2) * (PIX * TAPS);
    #pragma unroll
    for (int o = 0; o < TAPS; ++o) dst[lane * TAPS + o] = s[o];
  }
  __syncthreads();
  if (wave < 2) {
    const float* srcp = red + wave * (PIX * TAPS);
    #pragma unroll
    for (int o = 0; o < TAPS; ++o) s[o] += srcp[lane * TAPS + o];
  }
  if (wave == 1) {
    float* dst = red + (PIX * TAPS);
    #pragma unroll
    for (int o = 0; o < TAPS; ++o) dst[lane * TAPS + o] = s[o];
  }
  __syncthreads();

  // ---- Softmax: full 64-lane wave 0, one pixel per lane ----
  if (wave == 0) {
    const float* srcp = red + (PIX * TAPS);
    float t[TAPS];
    #pragma unroll
    for (int o = 0; o < TAPS; ++o)
      t[o] = s[o] + srcp[lane * TAPS + o] + beff[o];
    float m = t[0];
    #pragma unroll
    for (int o = 1; o < TAPS; ++o) m = fmaxf(m, t[o]);
    float sum = 0.f;
    #pragma unroll
    for (int o = 0; o < TAPS; ++o) { t[o] = __expf(t[o] - m); sum += t[o]; }
    float inv = 1.f / sum;
    #pragma unroll
    for (int o = 0; o < TAPS; ++o) red[lane * TAPS + o] = t[o] * inv;
  }
  __syncthreads();

  // ---- Phase 2: out[b,c,h,w] = sum_tap sfin[tap] * x[b,c,tap(h,w)] ----
  float acc[CPW];
  #pragma unroll
  for (int c = 0; c < CPW; ++c) acc[c] = 0.f;

  #pragma unroll 1
  for (int tap = 0; tap < TAPS; ++tap) {
    int i = tap / 5, j = tap % 5;
    int yy = h + 2 * i - 4;
    int xx = w + 2 * j - 4;
    float sv = red[lane * TAPS + tap];
    if (yy >= 0 && yy < HH && xx >= 0 && xx < WW) {
      const float* xp = xb + yy * WW + xx;
      #pragma unroll
      for (int c = 0; c < CPW; ++c)
        acc[c] = fmaf(sv, xp[(size_t)c * HW], acc[c]);
    }
  }

  float* ob = out + (size_t)b * CH * HW + (size_t)c0 * HW + hw;
  #pragma unroll
  for (int c = 0; c < CPW; ++c) ob[c * HW] = acc[c];
}

extern "C" void kernel_launch(void* const* d_in, const int* in_sizes, int n_in,
                              void* d_out, int out_size, void* d_ws, size_t ws_size,
                              hipStream_t stream) {
  const float* x  = (const float*)d_in[0];
  const float* w1 = (const float*)d_in[1];
  const float* b1 = (const float*)d_in[2];
  const float* w2 = (const float*)d_in[3];
  const float* b2 = (const float*)d_in[4];
  float* out  = (float*)d_out;
  float* weff = (float*)d_ws;                       // 40000 floats
  float* beff = weff + WEFF_N;                      // 25 floats

  weff_kernel<<<(WEFF_TOT + 63) / 64, 256, 0, stream>>>(
      w1, b1, w2, b2, weff, beff);
  picanet_main<<<NBLK, 256, 0, stream>>>(x, weff, beff, out);
}